// Round 8
// baseline (662.923 us; speedup 1.0000x reference)
//
#include <hip/hip_runtime.h>
#include <stdint.h>

// ---------------------------------------------------------------------------
// CrossAttention (b=16, c=1024, dim=1024), fp32 in/out, bf16 MFMA internally.
// R8: cvt of x/cond FUSED into Q/KV GEMMs (fp32 A reg-staged + in-register
// cvt + swizzled ds_write). Only weights are pre-converted (3 MB).
//   1. cvt_w: Wq->WQB, Wkv->WKVB (bf16)
//   2. Q  = x    @ WQB^T                    (bf16 out; A fp32 fused-cvt)
//   3. KV = cond @ WKVB^T -> K, V^T         (bf16; A fp32 fused-cvt)
//   4. S  = Q @ K^T * 1/32  per batch       (fp32)
//   5. P  = softmax_rows(S)                 (bf16, overlays Q)
//   6. out= P @ (V^T)^T  per batch          (fp32 -> d_out)
// GEMM: 256x256 tile, BK=64, 8 waves (2Mx4N), 2 phases/K-tile, cross-phase
// lgkm-pipelined ds_reads (R7), counted vmcnt, XOR-swizzled LDS, setprio,
// XCD swizzle. AFP32 path: A(t+3) fp32 loads issued ph(t,1), consumed
// (cvt+ds_write) ph(t+1,1) -> one-iteration (~1200cy) HBM lead.
// ---------------------------------------------------------------------------

typedef __bf16 bf16_t;
typedef bf16_t bf16x8 __attribute__((ext_vector_type(8)));
typedef float f32x4 __attribute__((ext_vector_type(4)));

#define AS1 __attribute__((address_space(1)))
#define AS3 __attribute__((address_space(3)))

__device__ __forceinline__ uint16_t f2bf(float f) {
  bf16_t h = (bf16_t)f;  // RNE
  return __builtin_bit_cast(uint16_t, h);
}

// ---- weights fp32 -> bf16 (Wq 1Mi + Wkv 2Mi floats = 786432 float4) ----
__global__ __launch_bounds__(256) void cvt_w(const float* __restrict__ wq,
                                             const float* __restrict__ wkv,
                                             uint16_t* __restrict__ WQB,
                                             uint16_t* __restrict__ WKVB) {
  int i = blockIdx.x * 256 + threadIdx.x;  // float4 index, < 786432
  const float* src;
  uint16_t* dst;
  int off;
  if (i < 262144) { src = wq; dst = WQB; off = i; }
  else { src = wkv; dst = WKVB; off = i - 262144; }
  float4 v = ((const float4*)src)[off];
  ushort4 o;
  o.x = f2bf(v.x); o.y = f2bf(v.y); o.z = f2bf(v.z); o.w = f2bf(v.w);
  ((ushort4*)dst)[off] = o;
}

// ---- stage one 256x64 bf16 K-tile (32 KiB) global -> LDS (4 loads/thread) --
// LDS dest linear (global_load_lds requirement); global SOURCE chunk-XOR
// pre-swizzled (rule #21) so readers use chunk^=(row&7), conflict-free.
__device__ __forceinline__ void stage_tile(const uint16_t* __restrict__ g,
                                           int ldK, uint16_t* lds, int tid) {
#pragma unroll
  for (int i = 0; i < 4; ++i) {
    int cix = i * 512 + tid;            // 16B-chunk index, 0..2047
    int row = cix >> 3;                 // 0..255
    int ch = cix & 7;                   // chunk within 128B row
    int sch = ch ^ (row & 7);           // involutive source swizzle
    const uint16_t* gp = g + row * ldK + sch * 8;
    __builtin_amdgcn_global_load_lds((AS1 void*)gp,
                                     (AS3 void*)((uint8_t*)lds + cix * 16), 16,
                                     0, 0);
  }
}

// ---- AFP32 helpers: A-tile 256x64 fp32 -> regs -> (cvt) swizzled LDS ----
// chunk j = kq*512+tid: row=j>>3, ch=j&7 (16B bf16 chunk = 32B fp32 = 2 float4)
#define ISSUE_A(TOFF)                                                       \
  _Pragma("unroll") for (int kq = 0; kq < 4; ++kq) {                        \
    int j = kq * 512 + tid;                                                 \
    const float* gp = At32 + (long long)(j >> 3) * K + (TOFF) + (j & 7) * 8;\
    areg[kq][0] = *(const f32x4*)gp;                                        \
    areg[kq][1] = *(const f32x4*)(gp + 4);                                  \
  }
#define WRITE_A(BUF)                                                        \
  _Pragma("unroll") for (int kq = 0; kq < 4; ++kq) {                        \
    int j = kq * 512 + tid;                                                 \
    int row = j >> 3, ch = j & 7;                                           \
    bf16x8 o;                                                               \
    o[0] = (bf16_t)areg[kq][0][0]; o[1] = (bf16_t)areg[kq][0][1];           \
    o[2] = (bf16_t)areg[kq][0][2]; o[3] = (bf16_t)areg[kq][0][3];           \
    o[4] = (bf16_t)areg[kq][1][0]; o[5] = (bf16_t)areg[kq][1][1];           \
    o[6] = (bf16_t)areg[kq][1][2]; o[7] = (bf16_t)areg[kq][1][3];           \
    *(bf16x8*)((uint8_t*)(BUF) + row * 128 + ((ch ^ (row & 7)) << 4)) = o;  \
  }

// ---- 256x256-tile A·B^T GEMM, bf16 MFMA, fp32 accum, lgkm-pipelined ----
// MODE 0: C0 = bf16; MODE 1: kv-split (K row-major / V^T LDS-transposed);
// MODE 2: C0 = fp32 * scale, batched via blockIdx.z.
// AFP32: A operand is fp32, converted in-kernel (Araw = const float*).
template <int MODE, bool AFP32>
__global__ __launch_bounds__(512, 2) void gemm_bt(
    const void* __restrict__ Araw, const uint16_t* __restrict__ B,
    void* __restrict__ C0, void* __restrict__ C1, int K, int N,
    long long sA, long long sB, long long sC, float scale) {
  // u16 units: A-buf0 [0,16384) A-buf1 [16384,32768) B-buf0 [32768,49152)
  // B-buf1 [49152,65536); each buf = 256 rows x 64 cols bf16
  __shared__ uint16_t smem[65536];

  const int tid = threadIdx.x;
  const int lane = tid & 63;
  const int wid = tid >> 6;
  const int wr = wid >> 2;    // 0..1 : M wave row (128 rows)
  const int wc = wid & 3;     // 0..3 : N wave col (64 cols)
  const int lr = lane & 15, lg = lane >> 4;
  const int ch0 = lr & 7;     // reader swizzle parity

  // T1: bijective XCD-chunked blockIdx swizzle (nwg % 8 == 0 always here)
  const int gx = gridDim.x, gy = gridDim.y;
  const int nwg = gx * gy * gridDim.z;
  int fid = blockIdx.x + gx * (blockIdx.y + gy * blockIdx.z);
  int swz = (fid & 7) * (nwg >> 3) + (fid >> 3);
  const int bx = swz % gx;
  const int rem = swz / gx;
  const int by = rem % gy;
  const int bz = rem / gy;

  const int row0 = by * 256;
  const int col0 = bx * 256;
  const float* At32 = nullptr;
  const uint16_t* At16 = nullptr;
  if constexpr (AFP32)
    At32 = (const float*)Araw + (long long)bz * sA + (long long)row0 * K;
  else
    At16 = (const uint16_t*)Araw + (long long)bz * sA + (long long)row0 * K;
  const uint16_t* Bt = B + (long long)bz * sB + (long long)col0 * K;

  const int NT = K >> 6;  // 16 here

  f32x4 areg[4][2];  // AFP32 in-flight fp32 A-chunks (32 VGPR)

  // ---- prologue ----
  if constexpr (AFP32) {
    stage_tile(Bt, K, smem + 32768, tid);
    stage_tile(Bt + 64, K, smem + 49152, tid);
    ISSUE_A(0);
    WRITE_A(smem);             // compiler waits A(0); B0/B1 may still fly
    ISSUE_A(64);
    WRITE_A(smem + 16384);     // compiler waits A(1) (drains B0/B1 too)
    if (NT > 2) ISSUE_A(128);  // A(2) in flight across the loop head
    asm volatile("s_waitcnt vmcnt(8) lgkmcnt(0)" ::: "memory");  // B0+writes
    __builtin_amdgcn_s_barrier();
  } else {
    stage_tile(At16, K, smem, tid);
    stage_tile(Bt, K, smem + 32768, tid);
    stage_tile(At16 + 64, K, smem + 16384, tid);
    stage_tile(Bt + 64, K, smem + 49152, tid);
    asm volatile("s_waitcnt vmcnt(8)" ::: "memory");
    __builtin_amdgcn_s_barrier();
  }

  f32x4 acc[8][4] = {};
  bf16x8 aA_[4][2];  // A(t,H0) frags (prefetched previous phase)
  bf16x8 aB_[4][2];  // A(t,H1) frags (prefetched in ph(t,0))
  bf16x8 bF[4][2];   // B(t) frags

  {  // preload aA_ = A(0,H0)
    const uint8_t* sa = (const uint8_t*)smem;
#pragma unroll
    for (int mi = 0; mi < 4; ++mi)
#pragma unroll
      for (int kk = 0; kk < 2; ++kk)
        aA_[mi][kk] = *(const bf16x8*)(sa + (wr * 128 + mi * 16 + lr) * 128 +
                                       (((kk * 4 + lg) ^ ch0) << 4));
  }

  for (int t = 0; t < NT; ++t) {
    const uint8_t* sa = (const uint8_t*)(smem + (t & 1) * 16384);
    const uint8_t* sb = (const uint8_t*)(smem + 32768 + (t & 1) * 16384);

    // ===== phase (t,0): MFMA {aA_, bF}; prefetch aB_ (stays outstanding) ====
#pragma unroll
    for (int nj = 0; nj < 4; ++nj)
#pragma unroll
      for (int kk = 0; kk < 2; ++kk)
        bF[nj][kk] = *(const bf16x8*)(sb + (wc * 64 + nj * 16 + lr) * 128 +
                                      (((kk * 4 + lg) ^ ch0) << 4));
#pragma unroll
    for (int mi = 0; mi < 4; ++mi)
#pragma unroll
      for (int kk = 0; kk < 2; ++kk)
        aB_[mi][kk] = *(const bf16x8*)(sa + (wr * 128 + 64 + mi * 16 + lr) * 128 +
                                       (((kk * 4 + lg) ^ ch0) << 4));
    __builtin_amdgcn_s_setprio(1);
#pragma unroll
    for (int kk = 0; kk < 2; ++kk)
#pragma unroll
      for (int mi = 0; mi < 4; ++mi)
#pragma unroll
        for (int nj = 0; nj < 4; ++nj)
          acc[mi][nj] = __builtin_amdgcn_mfma_f32_16x16x32_bf16(
              aA_[mi][kk], bF[nj][kk], acc[mi][nj], 0, 0, 0);
    __builtin_amdgcn_s_setprio(0);
    if constexpr (!AFP32) {
      if (t + 1 < NT) asm volatile("s_waitcnt vmcnt(4)" ::: "memory");
    }
    // WAR fence: drain aB_/bF reads of buf[t&1] before ph(t,1) writes it.
    asm volatile("s_waitcnt lgkmcnt(0)" ::: "memory");
    __builtin_amdgcn_s_barrier();

    // ===== phase (t,1): A-write + issues + stages; MFMA {aB_, bF}; refill ===
    if constexpr (AFP32) {
      if (t + 2 < NT) WRITE_A(smem + (t & 1) * 16384);  // compiler-waited
      if (t + 3 < NT) ISSUE_A((t + 3) * 64);
      if (t + 2 < NT)
        stage_tile(Bt + (t + 2) * 64, K, smem + 32768 + (t & 1) * 16384, tid);
    } else {
      if (t + 2 < NT) {
        stage_tile(At16 + (t + 2) * 64, K, smem + (t & 1) * 16384, tid);
        stage_tile(Bt + (t + 2) * 64, K, smem + 32768 + (t & 1) * 16384, tid);
      }
    }
    if (t + 1 < NT) {
      const uint8_t* sa2 = (const uint8_t*)(smem + ((t + 1) & 1) * 16384);
#pragma unroll
      for (int mi = 0; mi < 4; ++mi)
#pragma unroll
        for (int kk = 0; kk < 2; ++kk)
          aA_[mi][kk] = *(const bf16x8*)(sa2 + (wr * 128 + mi * 16 + lr) * 128 +
                                         (((kk * 4 + lg) ^ ch0) << 4));
    }
    __builtin_amdgcn_s_setprio(1);
#pragma unroll
    for (int kk = 0; kk < 2; ++kk)
#pragma unroll
      for (int mi = 0; mi < 4; ++mi)
#pragma unroll
        for (int nj = 0; nj < 4; ++nj)
          acc[4 + mi][nj] = __builtin_amdgcn_mfma_f32_16x16x32_bf16(
              aB_[mi][kk], bF[nj][kk], acc[4 + mi][nj], 0, 0, 0);
    __builtin_amdgcn_s_setprio(0);
    // derived counted waits: complete B(t+1) (read next phase); leave rest.
    if constexpr (AFP32) {
      if (t + 3 < NT)       // outstanding [B(t+1):4, A(t+3):8, B(t+2):4]
        asm volatile("s_waitcnt vmcnt(12)" ::: "memory");
      else if (t + 2 < NT)  // [B(t+1):4, B(t+2):4]
        asm volatile("s_waitcnt vmcnt(4)" ::: "memory");
      else if (t + 1 < NT)  // [B(t+1):4]
        asm volatile("s_waitcnt vmcnt(0)" ::: "memory");
    } else {
      if (t + 2 < NT)
        asm volatile("s_waitcnt vmcnt(8)" ::: "memory");
      else
        asm volatile("s_waitcnt vmcnt(0)" ::: "memory");
    }
    __builtin_amdgcn_s_barrier();
  }

  // ---- epilogue: C/D layout col=lane&15, row=(lane>>4)*4+j ----
  if (MODE == 1 && col0 >= 1024) {
    __syncthreads();
#pragma unroll
    for (int mi = 0; mi < 8; ++mi) {
#pragma unroll
      for (int ni = 0; ni < 4; ++ni) {
        const int cc = wc * 64 + ni * 16 + lr;
        const int jjb = wr * 128 + mi * 16 + lg * 4;
        ushort4 o;
        o.x = f2bf(acc[mi][ni][0]);
        o.y = f2bf(acc[mi][ni][1]);
        o.z = f2bf(acc[mi][ni][2]);
        o.w = f2bf(acc[mi][ni][3]);
        *(ushort4*)&smem[cc * 256 + (jjb ^ ((cc & 7) << 3))] = o;
      }
    }
    __syncthreads();
    const int b = row0 >> 10, jj0 = row0 & 1023;
    uint16_t* Vp = (uint16_t*)C1;
#pragma unroll
    for (int k = 0; k < 16; ++k) {
      const int cc = k * 16 + (tid >> 5);
      const int jb = (tid & 31) * 8;
      bf16x8 v = *(const bf16x8*)&smem[cc * 256 + (jb ^ ((cc & 7) << 3))];
      *(bf16x8*)(Vp + (long long)b * 1048576 +
                 (long long)(col0 - 1024 + cc) * 1024 + jj0 + jb) = v;
    }
    return;
  }
#pragma unroll
  for (int mi = 0; mi < 8; ++mi) {
#pragma unroll
    for (int ni = 0; ni < 4; ++ni) {
      const int row = row0 + wr * 128 + mi * 16 + lg * 4;
      const int col = col0 + wc * 64 + ni * 16 + lr;
      if (MODE == 0 || MODE == 1) {
        uint16_t* C = (uint16_t*)C0;
#pragma unroll
        for (int j = 0; j < 4; ++j)
          C[(long long)(row + j) * (MODE == 1 ? 1024 : N) + col] =
              f2bf(acc[mi][ni][j]);
      } else {
        float* C = (float*)C0;
#pragma unroll
        for (int j = 0; j < 4; ++j)
          C[(long long)bz * sC + (long long)(row + j) * N + col] =
              acc[mi][ni][j] * scale;
      }
    }
  }
}

// ---- row softmax: 16384 rows x 1024 fp32 -> bf16 ----
__global__ __launch_bounds__(256) void softmax_rows(const float* __restrict__ S,
                                                    uint16_t* __restrict__ P) {
  const int row = blockIdx.x;
  const int t = threadIdx.x;
  const int w = t >> 6, l = t & 63;
  __shared__ float red[8];

  const float4 v = ((const float4*)(S + (long long)row * 1024))[t];
  float m = fmaxf(fmaxf(v.x, v.y), fmaxf(v.z, v.w));
#pragma unroll
  for (int o = 1; o < 64; o <<= 1) m = fmaxf(m, __shfl_xor(m, o, 64));
  if (l == 0) red[w] = m;
  __syncthreads();
  m = fmaxf(fmaxf(red[0], red[1]), fmaxf(red[2], red[3]));

  float e0 = __expf(v.x - m), e1 = __expf(v.y - m);
  float e2 = __expf(v.z - m), e3 = __expf(v.w - m);
  float s = e0 + e1 + e2 + e3;
#pragma unroll
  for (int o = 1; o < 64; o <<= 1) s += __shfl_xor(s, o, 64);
  if (l == 0) red[4 + w] = s;
  __syncthreads();
  s = red[4] + red[5] + red[6] + red[7];
  const float inv = 1.0f / s;

  ushort4 o4;
  o4.x = f2bf(e0 * inv); o4.y = f2bf(e1 * inv);
  o4.z = f2bf(e2 * inv); o4.w = f2bf(e3 * inv);
  ((ushort4*)P)[(long long)row * 256 + t] = o4;
}

extern "C" void kernel_launch(void* const* d_in, const int* in_sizes, int n_in,
                              void* d_out, int out_size, void* d_ws, size_t ws_size,
                              hipStream_t stream) {
  const float* x    = (const float*)d_in[0];
  const float* cond = (const float*)d_in[1];
  const float* Wq   = (const float*)d_in[2];
  const float* Wkv  = (const float*)d_in[3];
  float* out = (float*)d_out;

  uint8_t* ws = (uint8_t*)d_ws;
  const long long MiB = 1ll << 20;
  // layout (166 MiB): Q (later P) @0, K @32, V^T @64, S @96 (fp32 64 MiB),
  // WQB @160, WKVB @162.
  uint16_t* Q    = (uint16_t*)(ws + 0 * MiB);
  uint16_t* Kb   = (uint16_t*)(ws + 32 * MiB);
  uint16_t* VT   = (uint16_t*)(ws + 64 * MiB);
  float*    S    = (float*)(ws + 96 * MiB);
  uint16_t* WQB  = (uint16_t*)(ws + 160 * MiB);
  uint16_t* WKVB = (uint16_t*)(ws + 162 * MiB);

  // 1. weights fp32->bf16 (786432 float4 / 256 = 3072 blocks)
  cvt_w<<<3072, 256, 0, stream>>>(Wq, Wkv, WQB, WKVB);

  // 2. Q = x @ WQB^T (fused cvt), M=16384 N=1024 K=1024 -> 256 blocks
  gemm_bt<0, true><<<dim3(4, 64, 1), 512, 0, stream>>>(
      x, WQB, Q, nullptr, 1024, 1024, 0, 0, 0, 1.0f);
  // 3. KV = cond @ WKVB^T (fused cvt) -> K, V^T (512 blocks)
  gemm_bt<1, true><<<dim3(8, 64, 1), 512, 0, stream>>>(
      cond, WKVB, Kb, VT, 1024, 2048, 0, 0, 0, 1.0f);
  // 4. S = Q @ K^T * 1/32, batched over 16 (256 blocks)
  gemm_bt<2, false><<<dim3(4, 4, 16), 512, 0, stream>>>(
      Q, Kb, S, nullptr, 1024, 1024, 1048576, 1048576, 1048576, 0.03125f);
  // 5. P = softmax(S) -> bf16, overlays Q
  softmax_rows<<<16384, 256, 0, stream>>>(S, Q);
  // 6. out = P @ (V^T)^T, batched over 16 (256 blocks)
  gemm_bt<2, false><<<dim3(4, 4, 16), 512, 0, stream>>>(
      Q, VT, out, nullptr, 1024, 1024, 1048576, 1048576, 1048576, 1.0f);
}

// Round 9
// 244.088 us; speedup vs baseline: 2.7159x; 2.7159x over previous
//
#include <hip/hip_runtime.h>
#include <stdint.h>

// ---------------------------------------------------------------------------
// CrossAttention (b=16, c=1024, dim=1024), fp32 in/out, bf16 MFMA internally.
//   1. cvt fp32->bf16 (one fused kernel): x->XB, cond->CB, Wq->WQB, Wkv->WKVB
//   2. Q  = XB @ WQB^T          gemm128 (128^2 tile, 1024 blocks, 2/CU)
//   3. KV = CB @ WKVB^T -> K, V^T   gemm_bt 256^2 (512 blocks, 2/CU)
//   4. S  = Q @ K^T * 1/32  per batch   gemm_bt 256^2 (L2-resident)
//   5. P  = softmax_rows(S)             (bf16, overlays Q)
//   6. out= P @ (V^T)^T  per batch      gemm_bt 256^2
// R9: Q moves to a 128^2-tile variant for 2 blocks/CU occupancy (cross-block
// stall hiding, m114/m97 mechanism). KV at 2/CU already runs ~916 TF with the
// 256^2 kernel; Q at 1/CU was stuck at 460 TF with identical code.
// ---------------------------------------------------------------------------

typedef __bf16 bf16_t;
typedef bf16_t bf16x8 __attribute__((ext_vector_type(8)));
typedef float f32x4 __attribute__((ext_vector_type(4)));

#define AS1 __attribute__((address_space(1)))
#define AS3 __attribute__((address_space(3)))

__device__ __forceinline__ uint16_t f2bf(float f) {
  bf16_t h = (bf16_t)f;  // RNE
  return __builtin_bit_cast(uint16_t, h);
}

// ---- fused fp32 -> bf16 conversion for all 4 tensors, float4-vectorized ----
// total float4 = (16777216 + 16777216 + 1048576 + 2097152)/4 = 9,175,040
__global__ __launch_bounds__(256) void cvt_all(
    const float* __restrict__ x, const float* __restrict__ c,
    const float* __restrict__ wq, const float* __restrict__ wkv,
    uint16_t* __restrict__ XB, uint16_t* __restrict__ CB,
    uint16_t* __restrict__ WQB, uint16_t* __restrict__ WKVB) {
  long i = (long)blockIdx.x * 256 + threadIdx.x;  // float4 index
  if (i >= 9175040) return;
  const float* src;
  uint16_t* dst;
  long off;
  if (i < 4194304) { src = x; dst = XB; off = i; }
  else if (i < 8388608) { src = c; dst = CB; off = i - 4194304; }
  else if (i < 8650752) { src = wq; dst = WQB; off = i - 8388608; }
  else { src = wkv; dst = WKVB; off = i - 8650752; }
  float4 v = ((const float4*)src)[off];
  ushort4 o;
  o.x = f2bf(v.x); o.y = f2bf(v.y); o.z = f2bf(v.z); o.w = f2bf(v.w);
  ((ushort4*)dst)[off] = o;
}

// ---- stage one 256x64 bf16 K-tile (32 KiB) global -> LDS (4 loads/thread,
// 512 threads). Source chunk-XOR pre-swizzled (rule #21); readers use
// chunk^=(row&7), conflict-free.
__device__ __forceinline__ void stage_tile(const uint16_t* __restrict__ g,
                                           int ldK, uint16_t* lds, int tid) {
#pragma unroll
  for (int i = 0; i < 4; ++i) {
    int cix = i * 512 + tid;            // 16B-chunk index, 0..2047
    int row = cix >> 3;                 // 0..255
    int ch = cix & 7;
    int sch = ch ^ (row & 7);
    const uint16_t* gp = g + row * ldK + sch * 8;
    __builtin_amdgcn_global_load_lds((AS1 void*)gp,
                                     (AS3 void*)((uint8_t*)lds + cix * 16), 16,
                                     0, 0);
  }
}

// ---- stage one 128x64 bf16 K-tile (16 KiB), 256 threads, 4 loads/thread ----
__device__ __forceinline__ void stage128(const uint16_t* __restrict__ g,
                                         int ldK, uint16_t* lds, int tid) {
#pragma unroll
  for (int i = 0; i < 4; ++i) {
    int cix = i * 256 + tid;            // 16B-chunk index, 0..1023
    int row = cix >> 3;                 // 0..127
    int ch = cix & 7;
    int sch = ch ^ (row & 7);
    const uint16_t* gp = g + row * ldK + sch * 8;
    __builtin_amdgcn_global_load_lds((AS1 void*)gp,
                                     (AS3 void*)((uint8_t*)lds + cix * 16), 16,
                                     0, 0);
  }
}

// ---- 256x256-tile A·B^T GEMM, bf16 in, fp32 accum, lgkm-pipelined (R7) ----
// MODE 1: kv-split: col<1024 -> K row-major; col>=1024 -> V^T (LDS transpose)
// MODE 2: C0 = fp32 * scale, batched via blockIdx.z
template <int MODE>
__global__ __launch_bounds__(512, 2) void gemm_bt(
    const uint16_t* __restrict__ A, const uint16_t* __restrict__ B,
    void* __restrict__ C0, void* __restrict__ C1, int K, int N,
    long long sA, long long sB, long long sC, float scale) {
  // u16: A-buf0 [0,16384) A-buf1 [16384,32768) B-buf0 [32768,49152)
  // B-buf1 [49152,65536); each buf = 256 rows x 64 cols bf16
  __shared__ uint16_t smem[65536];

  const int tid = threadIdx.x;
  const int lane = tid & 63;
  const int wid = tid >> 6;
  const int wr = wid >> 2;    // 0..1
  const int wc = wid & 3;     // 0..3
  const int lr = lane & 15, lg = lane >> 4;
  const int ch0 = lr & 7;

  const int gx = gridDim.x, gy = gridDim.y;
  const int nwg = gx * gy * gridDim.z;
  int fid = blockIdx.x + gx * (blockIdx.y + gy * blockIdx.z);
  int swz = (fid & 7) * (nwg >> 3) + (fid >> 3);
  const int bx = swz % gx;
  const int rem = swz / gx;
  const int by = rem % gy;
  const int bz = rem / gy;

  const int row0 = by * 256;
  const int col0 = bx * 256;
  const uint16_t* At = A + (long long)bz * sA + (long long)row0 * K;
  const uint16_t* Bt = B + (long long)bz * sB + (long long)col0 * K;

  const int NT = K >> 6;

  stage_tile(At, K, smem, tid);
  stage_tile(Bt, K, smem + 32768, tid);
  stage_tile(At + 64, K, smem + 16384, tid);
  stage_tile(Bt + 64, K, smem + 49152, tid);
  asm volatile("s_waitcnt vmcnt(8)" ::: "memory");
  __builtin_amdgcn_s_barrier();

  f32x4 acc[8][4] = {};
  bf16x8 aA_[4][2], aB_[4][2], bF[4][2];

  {
    const uint8_t* sa = (const uint8_t*)smem;
#pragma unroll
    for (int mi = 0; mi < 4; ++mi)
#pragma unroll
      for (int kk = 0; kk < 2; ++kk)
        aA_[mi][kk] = *(const bf16x8*)(sa + (wr * 128 + mi * 16 + lr) * 128 +
                                       (((kk * 4 + lg) ^ ch0) << 4));
  }

  for (int t = 0; t < NT; ++t) {
    const uint8_t* sa = (const uint8_t*)(smem + (t & 1) * 16384);
    const uint8_t* sb = (const uint8_t*)(smem + 32768 + (t & 1) * 16384);

    // phase (t,0): MFMA {aA_, bF}; prefetch aB_ (stays outstanding)
#pragma unroll
    for (int nj = 0; nj < 4; ++nj)
#pragma unroll
      for (int kk = 0; kk < 2; ++kk)
        bF[nj][kk] = *(const bf16x8*)(sb + (wc * 64 + nj * 16 + lr) * 128 +
                                      (((kk * 4 + lg) ^ ch0) << 4));
#pragma unroll
    for (int mi = 0; mi < 4; ++mi)
#pragma unroll
      for (int kk = 0; kk < 2; ++kk)
        aB_[mi][kk] = *(const bf16x8*)(sa + (wr * 128 + 64 + mi * 16 + lr) * 128 +
                                       (((kk * 4 + lg) ^ ch0) << 4));
    __builtin_amdgcn_s_setprio(1);
#pragma unroll
    for (int kk = 0; kk < 2; ++kk)
#pragma unroll
      for (int mi = 0; mi < 4; ++mi)
#pragma unroll
        for (int nj = 0; nj < 4; ++nj)
          acc[mi][nj] = __builtin_amdgcn_mfma_f32_16x16x32_bf16(
              aA_[mi][kk], bF[nj][kk], acc[mi][nj], 0, 0, 0);
    __builtin_amdgcn_s_setprio(0);
    if (t + 1 < NT) asm volatile("s_waitcnt vmcnt(4)" ::: "memory");
    asm volatile("s_waitcnt lgkmcnt(0)" ::: "memory");
    __builtin_amdgcn_s_barrier();

    // phase (t,1): stages; MFMA {aB_, bF}; refill aA_
    if (t + 2 < NT) {
      stage_tile(At + (t + 2) * 64, K, smem + (t & 1) * 16384, tid);
      stage_tile(Bt + (t + 2) * 64, K, smem + 32768 + (t & 1) * 16384, tid);
    }
    if (t + 1 < NT) {
      const uint8_t* sa2 = (const uint8_t*)(smem + ((t + 1) & 1) * 16384);
#pragma unroll
      for (int mi = 0; mi < 4; ++mi)
#pragma unroll
        for (int kk = 0; kk < 2; ++kk)
          aA_[mi][kk] = *(const bf16x8*)(sa2 + (wr * 128 + mi * 16 + lr) * 128 +
                                         (((kk * 4 + lg) ^ ch0) << 4));
    }
    __builtin_amdgcn_s_setprio(1);
#pragma unroll
    for (int kk = 0; kk < 2; ++kk)
#pragma unroll
      for (int mi = 0; mi < 4; ++mi)
#pragma unroll
        for (int nj = 0; nj < 4; ++nj)
          acc[4 + mi][nj] = __builtin_amdgcn_mfma_f32_16x16x32_bf16(
              aB_[mi][kk], bF[nj][kk], acc[4 + mi][nj], 0, 0, 0);
    __builtin_amdgcn_s_setprio(0);
    if (t + 2 < NT)
      asm volatile("s_waitcnt vmcnt(8)" ::: "memory");
    else
      asm volatile("s_waitcnt vmcnt(0)" ::: "memory");
    __builtin_amdgcn_s_barrier();
  }

  // epilogue: C/D layout col=lane&15, row=(lane>>4)*4+j
  if (MODE == 1 && col0 >= 1024) {
    __syncthreads();
#pragma unroll
    for (int mi = 0; mi < 8; ++mi) {
#pragma unroll
      for (int ni = 0; ni < 4; ++ni) {
        const int cc = wc * 64 + ni * 16 + lr;
        const int jjb = wr * 128 + mi * 16 + lg * 4;
        ushort4 o;
        o.x = f2bf(acc[mi][ni][0]);
        o.y = f2bf(acc[mi][ni][1]);
        o.z = f2bf(acc[mi][ni][2]);
        o.w = f2bf(acc[mi][ni][3]);
        *(ushort4*)&smem[cc * 256 + (jjb ^ ((cc & 7) << 3))] = o;
      }
    }
    __syncthreads();
    const int b = row0 >> 10, jj0 = row0 & 1023;
    uint16_t* Vp = (uint16_t*)C1;
#pragma unroll
    for (int k = 0; k < 16; ++k) {
      const int cc = k * 16 + (tid >> 5);
      const int jb = (tid & 31) * 8;
      bf16x8 v = *(const bf16x8*)&smem[cc * 256 + (jb ^ ((cc & 7) << 3))];
      *(bf16x8*)(Vp + (long long)b * 1048576 +
                 (long long)(col0 - 1024 + cc) * 1024 + jj0 + jb) = v;
    }
    return;
  }
#pragma unroll
  for (int mi = 0; mi < 8; ++mi) {
#pragma unroll
    for (int ni = 0; ni < 4; ++ni) {
      const int row = row0 + wr * 128 + mi * 16 + lg * 4;
      const int col = col0 + wc * 64 + ni * 16 + lr;
      if (MODE == 1) {
        uint16_t* C = (uint16_t*)C0;
#pragma unroll
        for (int j = 0; j < 4; ++j)
          C[(long long)(row + j) * 1024 + col] = f2bf(acc[mi][ni][j]);
      } else {
        float* C = (float*)C0;
#pragma unroll
        for (int j = 0; j < 4; ++j)
          C[(long long)bz * sC + (long long)(row + j) * N + col] =
              acc[mi][ni][j] * scale;
      }
    }
  }
}

// ---- 128x128-tile A·B^T GEMM, bf16 in/out, 4 waves, 64 KiB LDS (2/CU) ----
// Same lgkm-pipelined 2-phase schedule; phase halves over mi (0,1 | 2,3).
__global__ __launch_bounds__(256, 2) void gemm128(
    const uint16_t* __restrict__ A, const uint16_t* __restrict__ B,
    uint16_t* __restrict__ C, int K, int N) {
  // u16: A0 [0,8192) A1 [8192,16384) B0 [16384,24576) B1 [24576,32768)
  __shared__ uint16_t smem[32768];

  const int tid = threadIdx.x;
  const int lane = tid & 63;
  const int wid = tid >> 6;   // 0..3
  const int wr = wid >> 1;    // 0..1 : M wave row (64 rows)
  const int wc = wid & 1;     // 0..1 : N wave col (64 cols)
  const int lr = lane & 15, lg = lane >> 4;
  const int ch0 = lr & 7;

  const int gx = gridDim.x;
  const int nwg = gx * gridDim.y;
  int fid = blockIdx.x + gx * blockIdx.y;
  int swz = (fid & 7) * (nwg >> 3) + (fid >> 3);
  const int bx = swz % gx;
  const int by = swz / gx;

  const int row0 = by * 128;
  const int col0 = bx * 128;
  const uint16_t* At = A + (long long)row0 * K;
  const uint16_t* Bt = B + (long long)col0 * K;

  const int NT = K >> 6;

  stage128(At, K, smem, tid);
  stage128(Bt, K, smem + 16384, tid);
  stage128(At + 64, K, smem + 8192, tid);
  stage128(Bt + 64, K, smem + 24576, tid);
  asm volatile("s_waitcnt vmcnt(8)" ::: "memory");
  __builtin_amdgcn_s_barrier();

  f32x4 acc[4][4] = {};
  bf16x8 aA_[2][2], aB_[2][2], bF[4][2];

  {
    const uint8_t* sa = (const uint8_t*)smem;
#pragma unroll
    for (int mi = 0; mi < 2; ++mi)
#pragma unroll
      for (int kk = 0; kk < 2; ++kk)
        aA_[mi][kk] = *(const bf16x8*)(sa + (wr * 64 + mi * 16 + lr) * 128 +
                                       (((kk * 4 + lg) ^ ch0) << 4));
  }

  for (int t = 0; t < NT; ++t) {
    const uint8_t* sa = (const uint8_t*)(smem + (t & 1) * 8192);
    const uint8_t* sb = (const uint8_t*)(smem + 16384 + (t & 1) * 8192);

    // phase (t,0): MFMA {aA_ (mi 0,1), bF}; prefetch aB_ (mi 2,3)
#pragma unroll
    for (int nj = 0; nj < 4; ++nj)
#pragma unroll
      for (int kk = 0; kk < 2; ++kk)
        bF[nj][kk] = *(const bf16x8*)(sb + (wc * 64 + nj * 16 + lr) * 128 +
                                      (((kk * 4 + lg) ^ ch0) << 4));
#pragma unroll
    for (int mi = 0; mi < 2; ++mi)
#pragma unroll
      for (int kk = 0; kk < 2; ++kk)
        aB_[mi][kk] = *(const bf16x8*)(sa + (wr * 64 + 32 + mi * 16 + lr) * 128 +
                                       (((kk * 4 + lg) ^ ch0) << 4));
    __builtin_amdgcn_s_setprio(1);
#pragma unroll
    for (int kk = 0; kk < 2; ++kk)
#pragma unroll
      for (int mi = 0; mi < 2; ++mi)
#pragma unroll
        for (int nj = 0; nj < 4; ++nj)
          acc[mi][nj] = __builtin_amdgcn_mfma_f32_16x16x32_bf16(
              aA_[mi][kk], bF[nj][kk], acc[mi][nj], 0, 0, 0);
    __builtin_amdgcn_s_setprio(0);
    if (t + 1 < NT) asm volatile("s_waitcnt vmcnt(4)" ::: "memory");
    asm volatile("s_waitcnt lgkmcnt(0)" ::: "memory");
    __builtin_amdgcn_s_barrier();

    // phase (t,1): stages; MFMA {aB_, bF}; refill aA_ from buf[(t+1)&1]
    if (t + 2 < NT) {
      stage128(At + (t + 2) * 64, K, smem + (t & 1) * 8192, tid);
      stage128(Bt + (t + 2) * 64, K, smem + 16384 + (t & 1) * 8192, tid);
    }
    if (t + 1 < NT) {
      const uint8_t* sa2 = (const uint8_t*)(smem + ((t + 1) & 1) * 8192);
#pragma unroll
      for (int mi = 0; mi < 2; ++mi)
#pragma unroll
        for (int kk = 0; kk < 2; ++kk)
          aA_[mi][kk] = *(const bf16x8*)(sa2 + (wr * 64 + mi * 16 + lr) * 128 +
                                         (((kk * 4 + lg) ^ ch0) << 4));
    }
    __builtin_amdgcn_s_setprio(1);
#pragma unroll
    for (int kk = 0; kk < 2; ++kk)
#pragma unroll
      for (int mi = 0; mi < 2; ++mi)
#pragma unroll
        for (int nj = 0; nj < 4; ++nj)
          acc[2 + mi][nj] = __builtin_amdgcn_mfma_f32_16x16x32_bf16(
              aB_[mi][kk], bF[nj][kk], acc[2 + mi][nj], 0, 0, 0);
    __builtin_amdgcn_s_setprio(0);
    if (t + 2 < NT)
      asm volatile("s_waitcnt vmcnt(8)" ::: "memory");
    else
      asm volatile("s_waitcnt vmcnt(0)" ::: "memory");
    __builtin_amdgcn_s_barrier();
  }

#pragma unroll
  for (int mi = 0; mi < 4; ++mi) {
#pragma unroll
    for (int ni = 0; ni < 4; ++ni) {
      const int row = row0 + wr * 64 + mi * 16 + lg * 4;
      const int col = col0 + wc * 64 + ni * 16 + lr;
#pragma unroll
      for (int j = 0; j < 4; ++j)
        C[(long long)(row + j) * N + col] = f2bf(acc[mi][ni][j]);
    }
  }
}

// ---- row softmax: 16384 rows x 1024 fp32 -> bf16 ----
__global__ __launch_bounds__(256) void softmax_rows(const float* __restrict__ S,
                                                    uint16_t* __restrict__ P) {
  const int row = blockIdx.x;
  const int t = threadIdx.x;
  const int w = t >> 6, l = t & 63;
  __shared__ float red[8];

  const float4 v = ((const float4*)(S + (long long)row * 1024))[t];
  float m = fmaxf(fmaxf(v.x, v.y), fmaxf(v.z, v.w));
#pragma unroll
  for (int o = 1; o < 64; o <<= 1) m = fmaxf(m, __shfl_xor(m, o, 64));
  if (l == 0) red[w] = m;
  __syncthreads();
  m = fmaxf(fmaxf(red[0], red[1]), fmaxf(red[2], red[3]));

  float e0 = __expf(v.x - m), e1 = __expf(v.y - m);
  float e2 = __expf(v.z - m), e3 = __expf(v.w - m);
  float s = e0 + e1 + e2 + e3;
#pragma unroll
  for (int o = 1; o < 64; o <<= 1) s += __shfl_xor(s, o, 64);
  if (l == 0) red[4 + w] = s;
  __syncthreads();
  s = red[4] + red[5] + red[6] + red[7];
  const float inv = 1.0f / s;

  ushort4 o4;
  o4.x = f2bf(e0 * inv); o4.y = f2bf(e1 * inv);
  o4.z = f2bf(e2 * inv); o4.w = f2bf(e3 * inv);
  ((ushort4*)P)[(long long)row * 256 + t] = o4;
}

extern "C" void kernel_launch(void* const* d_in, const int* in_sizes, int n_in,
                              void* d_out, int out_size, void* d_ws, size_t ws_size,
                              hipStream_t stream) {
  const float* x    = (const float*)d_in[0];
  const float* cond = (const float*)d_in[1];
  const float* Wq   = (const float*)d_in[2];
  const float* Wkv  = (const float*)d_in[3];
  float* out = (float*)d_out;

  uint8_t* ws = (uint8_t*)d_ws;
  const long long MiB = 1ll << 20;
  // layout (166 MiB peak): S(fp32,64Mi) overlays XB+CB; P overlays Q.
  uint16_t* XB   = (uint16_t*)(ws + 0 * MiB);    // 32 MiB
  uint16_t* CB   = (uint16_t*)(ws + 32 * MiB);   // 32 MiB
  float*    S    = (float*)(ws + 0 * MiB);       // 64 MiB (after projections)
  uint16_t* WQB  = (uint16_t*)(ws + 64 * MiB);   // 2 MiB
  uint16_t* WKVB = (uint16_t*)(ws + 66 * MiB);   // 4 MiB
  uint16_t* Q    = (uint16_t*)(ws + 70 * MiB);   // 32 MiB (later P)
  uint16_t* Kb   = (uint16_t*)(ws + 102 * MiB);  // 32 MiB
  uint16_t* VT   = (uint16_t*)(ws + 134 * MiB);  // 32 MiB

  // 1. fused conversions
  cvt_all<<<35840, 256, 0, stream>>>(x, cond, Wq, Wkv, XB, CB, WQB, WKVB);

  // 2. Q = XB @ WQB^T (M=16384, N=1024, K=1024): 128^2 tiles, 1024 blocks
  gemm128<<<dim3(8, 128), 256, 0, stream>>>(XB, WQB, Q, 1024, 1024);
  // 3. KV = CB @ WKVB^T -> K, V^T (512 blocks, 2/CU)
  gemm_bt<1><<<dim3(8, 64, 1), 512, 0, stream>>>(CB, WKVB, Kb, VT, 1024, 2048,
                                                 0, 0, 0, 1.0f);
  // 4. S = Q @ K^T * 1/32, batched over 16 (256 blocks)
  gemm_bt<2><<<dim3(4, 4, 16), 512, 0, stream>>>(Q, Kb, S, nullptr, 1024, 1024,
                                                 1048576, 1048576, 1048576,
                                                 0.03125f);
  // 5. P = softmax(S) -> bf16, overlays Q
  softmax_rows<<<16384, 256, 0, stream>>>(S, Q);
  // 6. out = P @ (V^T)^T, batched over 16 (256 blocks)
  gemm_bt<2><<<dim3(4, 4, 16), 512, 0, stream>>>(Q, VT, out, nullptr, 1024,
                                                 1024, 1048576, 1048576,
                                                 1048576, 1.0f);
}